// Round 3
// baseline (1479.405 us; speedup 1.0000x reference)
//
#include <hip/hip_runtime.h>

#define NB 4
#define CIN 256
#define CO 512
#define HH 128
#define WW 128
#define PP (HH*WW)     // 16384
#define HO 64
#define TT (HO*HO)     // 4096
#define EPSL 1e-5f

// ---------------------------------------------------------------------------
// Generic f32 GEMM: OUT[b][o][t] = sum_k W[o][k]*IN[b][k][t] + bias[o]
// 64x64 tile, 256 threads, 4x4 per thread, BK=16. o-range via gridDim.y.
// ---------------------------------------------------------------------------
template<int K>
__global__ __launch_bounds__(256) void gemm_f32(
    const float* __restrict__ Wm, const float* __restrict__ bias,
    const float* __restrict__ IN, float* __restrict__ OUT, int T, int Ochan)
{
  const int b = blockIdx.z, o0 = blockIdx.y*64, t0 = blockIdx.x*64;
  const int tid = threadIdx.x, tx = tid & 15, ty = tid >> 4;
  __shared__ float Ws[16][64];
  __shared__ float Is[16][64];
  float acc[4][4] = {};
  for (int k0 = 0; k0 < K; k0 += 16) {
    { // stage W
      int oo = tid & 63, kk0 = (tid >> 6) * 4;
      const float4 w4 = *reinterpret_cast<const float4*>(&Wm[(size_t)(o0+oo)*K + k0 + kk0]);
      Ws[kk0+0][oo] = w4.x; Ws[kk0+1][oo] = w4.y; Ws[kk0+2][oo] = w4.z; Ws[kk0+3][oo] = w4.w;
    }
    { // stage IN
      int tt = tid & 63, kkb = tid >> 6;
      const float* src = &IN[((size_t)b*K + k0 + kkb)*T + t0 + tt];
      #pragma unroll
      for (int s = 0; s < 4; ++s) Is[kkb + s*4][tt] = src[(size_t)(s*4)*T];
    }
    __syncthreads();
    #pragma unroll
    for (int kk = 0; kk < 16; ++kk) {
      float4 av = *reinterpret_cast<const float4*>(&Ws[kk][ty*4]);
      float4 bv = *reinterpret_cast<const float4*>(&Is[kk][tx*4]);
      float a[4] = {av.x,av.y,av.z,av.w}, c[4] = {bv.x,bv.y,bv.z,bv.w};
      #pragma unroll
      for (int j = 0; j < 4; ++j)
        #pragma unroll
        for (int i = 0; i < 4; ++i) acc[j][i] += a[j]*c[i];
    }
    __syncthreads();
  }
  #pragma unroll
  for (int j = 0; j < 4; ++j) {
    int o = o0 + ty*4 + j;
    float bs = bias[o];
    float4 r = make_float4(acc[j][0]+bs, acc[j][1]+bs, acc[j][2]+bs, acc[j][3]+bs);
    *reinterpret_cast<float4*>(&OUT[((size_t)b*Ochan + o)*T + t0 + tx*4]) = r;
  }
}

// ---------------------------------------------------------------------------
// Patchify conv as GEMM (f32 out): K = CIN*4, k = i*4 + kh*2 + kw.
// ---------------------------------------------------------------------------
__global__ __launch_bounds__(256) void gemm_conv(
    const float* __restrict__ Wc, const float* __restrict__ cb,
    const float* __restrict__ x_in, float* __restrict__ TMP)
{
  const int b = blockIdx.z, o0 = blockIdx.y*64, ho = blockIdx.x;
  const int tid = threadIdx.x, tx = tid & 15, ty = tid >> 4;
  __shared__ float Ws[16][64];
  __shared__ float Is[16][64];
  float acc[4][4] = {};
  const int K = CIN*4;
  for (int k0 = 0; k0 < K; k0 += 16) {
    {
      int oo = tid & 63, kk0 = (tid >> 6) * 4;
      const float4 w4 = *reinterpret_cast<const float4*>(&Wc[(size_t)(o0+oo)*K + k0 + kk0]);
      Ws[kk0+0][oo] = w4.x; Ws[kk0+1][oo] = w4.y; Ws[kk0+2][oo] = w4.z; Ws[kk0+3][oo] = w4.w;
    }
    {
      int tt = tid & 63, kkb = tid >> 6;
      #pragma unroll
      for (int s = 0; s < 4; ++s) {
        int kk = kkb + s*4, k = k0 + kk;
        int i = k >> 2, kh = (k >> 1) & 1, kw = k & 1;
        Is[kk][tt] = x_in[(((size_t)b*CIN + i)*HH + 2*ho + kh)*WW + 2*tt + kw];
      }
    }
    __syncthreads();
    #pragma unroll
    for (int kk = 0; kk < 16; ++kk) {
      float4 av = *reinterpret_cast<const float4*>(&Ws[kk][ty*4]);
      float4 bv = *reinterpret_cast<const float4*>(&Is[kk][tx*4]);
      float a[4] = {av.x,av.y,av.z,av.w}, c[4] = {bv.x,bv.y,bv.z,bv.w};
      #pragma unroll
      for (int j = 0; j < 4; ++j)
        #pragma unroll
        for (int i = 0; i < 4; ++i) acc[j][i] += a[j]*c[i];
    }
    __syncthreads();
  }
  #pragma unroll
  for (int j = 0; j < 4; ++j) {
    int o = o0 + ty*4 + j;
    float bs = cb[o];
    float4 r = make_float4(acc[j][0]+bs, acc[j][1]+bs, acc[j][2]+bs, acc[j][3]+bs);
    *reinterpret_cast<float4*>(&TMP[((size_t)b*CO + o)*TT + ho*64 + tx*4]) = r;
  }
}

// ---------------------------------------------------------------------------
// Mt[i][j] = sum_f k_w[f][i] * q_w[f][j]   (256 x 512), tiled A^T*B.
// ---------------------------------------------------------------------------
__global__ __launch_bounds__(256) void gemm_tn(
    const float* __restrict__ A,   // k_w (CO, CIN)
    const float* __restrict__ B,   // q_w (CO, CO)
    float* __restrict__ Mt)        // (CIN, CO)
{
  const int i0 = blockIdx.y*64, j0 = blockIdx.x*64;
  const int tid = threadIdx.x, tx = tid & 15, ty = tid >> 4;
  __shared__ float As[16][64];
  __shared__ float Bs[16][64];
  float acc[4][4] = {};
  for (int f0 = 0; f0 < CO; f0 += 16) {
    int tt = tid & 63, kkb = tid >> 6;
    #pragma unroll
    for (int s = 0; s < 4; ++s) {
      As[kkb+s*4][tt] = A[(size_t)(f0+kkb+s*4)*CIN + i0 + tt];
      Bs[kkb+s*4][tt] = B[(size_t)(f0+kkb+s*4)*CO  + j0 + tt];
    }
    __syncthreads();
    #pragma unroll
    for (int kk = 0; kk < 16; ++kk) {
      float4 av = *reinterpret_cast<const float4*>(&As[kk][ty*4]);
      float4 bv = *reinterpret_cast<const float4*>(&Bs[kk][tx*4]);
      float a[4] = {av.x,av.y,av.z,av.w}, c[4] = {bv.x,bv.y,bv.z,bv.w};
      #pragma unroll
      for (int j = 0; j < 4; ++j)
        #pragma unroll
        for (int i = 0; i < 4; ++i) acc[j][i] += a[j]*c[i];
    }
    __syncthreads();
  }
  #pragma unroll
  for (int j = 0; j < 4; ++j) {
    float4 r = make_float4(acc[j][0], acc[j][1], acc[j][2], acc[j][3]);
    *reinterpret_cast<float4*>(&Mt[(size_t)(i0+ty*4+j)*CO + j0 + tx*4]) = r;
  }
}

// qbk[i] = sum_f q_b[f] * k_w[f][i]
__global__ void qbk_kernel(const float* __restrict__ q_b,
                           const float* __restrict__ k_w, float* __restrict__ qbk)
{
  int i = threadIdx.x;
  float s = 0.f;
  for (int f = 0; f < CO; ++f) s += q_b[f]*k_w[(size_t)f*CIN + i];
  qbk[i] = s;
}

// ---------------------------------------------------------------------------
// Attention: logits from qk (f32) and x_in (f32), softmax over 4 window
// positions, then xp[i][t] = sum_w p_w * x_in[i][pix_w].  64 t x 4 i-groups.
// ---------------------------------------------------------------------------
__global__ __launch_bounds__(256) void att_xp(
    const float* __restrict__ qk, const float* __restrict__ x_in,
    float* __restrict__ xp)
{
  const int b = blockIdx.y;
  const int tl = threadIdx.x & 63, cg = threadIdx.x >> 6;
  const int t = blockIdx.x*64 + tl;
  const int ho = t >> 6, wo = t & 63;
  const size_t p00 = (size_t)(2*ho)*WW + 2*wo;  // (kh,kw): +0,+1,+128,+129

  float a0=0.f, a1=0.f, a2=0.f, a3=0.f;
  for (int i = cg*64; i < cg*64 + 64; ++i) {
    float qv = qk[((size_t)b*CIN + i)*TT + t];
    const float* xr = &x_in[((size_t)b*CIN + i)*PP + p00];
    float2 x01 = *reinterpret_cast<const float2*>(xr);
    float2 x23 = *reinterpret_cast<const float2*>(xr + WW);
    a0 += qv*x01.x; a1 += qv*x01.y; a2 += qv*x23.x; a3 += qv*x23.y;
  }
  __shared__ float attp[4][64][4];
  attp[cg][tl][0] = a0; attp[cg][tl][1] = a1;
  attp[cg][tl][2] = a2; attp[cg][tl][3] = a3;
  __syncthreads();
  a0 = attp[0][tl][0] + attp[1][tl][0] + attp[2][tl][0] + attp[3][tl][0];
  a1 = attp[0][tl][1] + attp[1][tl][1] + attp[2][tl][1] + attp[3][tl][1];
  a2 = attp[0][tl][2] + attp[1][tl][2] + attp[2][tl][2] + attp[3][tl][2];
  a3 = attp[0][tl][3] + attp[1][tl][3] + attp[2][tl][3] + attp[3][tl][3];
  float m = fmaxf(fmaxf(a0,a1), fmaxf(a2,a3));
  float e0 = expf(a0-m), e1 = expf(a1-m), e2 = expf(a2-m), e3 = expf(a3-m);
  float inv = 1.f / (e0+e1+e2+e3);
  float p0 = e0*inv, p1 = e1*inv, p2 = e2*inv, p3 = e3*inv;

  for (int i = cg*64; i < cg*64 + 64; ++i) {
    const float* xr = &x_in[((size_t)b*CIN + i)*PP + p00];
    float2 x01 = *reinterpret_cast<const float2*>(xr);
    float2 x23 = *reinterpret_cast<const float2*>(xr + WW);
    xp[((size_t)b*CIN + i)*TT + t] = p0*x01.x + p1*x01.y + p2*x23.x + p3*x23.y;
  }
}

// ---------------------------------------------------------------------------
// Channel LayerNorm over C=512 of f32 TMP; x_out = (ADD? x_out : 0) + LN.
// ---------------------------------------------------------------------------
template<bool ADD>
__global__ __launch_bounds__(256) void ln_channel(
    const float* __restrict__ TMP, const float* __restrict__ g, const float* __restrict__ be,
    float* __restrict__ XOUT)
{
  const int b = blockIdx.y;
  const int tl = threadIdx.x & 63, cg = threadIdx.x >> 6;
  const int t = blockIdx.x*64 + tl;
  float s = 0.f, s2 = 0.f;
  for (int c = cg*128; c < cg*128 + 128; ++c) {
    float v = TMP[((size_t)b*CO + c)*TT + t];
    s += v; s2 += v*v;
  }
  __shared__ float red[2][4][64];
  red[0][cg][tl] = s; red[1][cg][tl] = s2;
  __syncthreads();
  float S  = red[0][0][tl] + red[0][1][tl] + red[0][2][tl] + red[0][3][tl];
  float S2 = red[1][0][tl] + red[1][1][tl] + red[1][2][tl] + red[1][3][tl];
  float mu = S * (1.f/CO);
  float var = S2 * (1.f/CO) - mu*mu;
  float rstd = rsqrtf(var + EPSL);
  for (int c = cg*128; c < cg*128 + 128; ++c) {
    size_t idx = ((size_t)b*CO + c)*TT + t;
    float v = TMP[idx];
    float r = g[c]*(v - mu)*rstd + be[c];
    XOUT[idx] = ADD ? (XOUT[idx] + r) : r;
  }
}

// ---------------------------------------------------------------------------
extern "C" void kernel_launch(void* const* d_in, const int* in_sizes, int n_in,
                              void* d_out, int out_size, void* d_ws, size_t ws_size,
                              hipStream_t stream) {
  const float* x_in   = (const float*)d_in[0];
  const float* conv_w = (const float*)d_in[1];
  const float* conv_b = (const float*)d_in[2];
  const float* k_w    = (const float*)d_in[3];
  const float* q_w    = (const float*)d_in[5];
  const float* q_b    = (const float*)d_in[6];
  const float* v_w    = (const float*)d_in[7];
  const float* v_b    = (const float*)d_in[8];
  const float* mlp_w  = (const float*)d_in[9];
  const float* mlp_b  = (const float*)d_in[10];
  const float* lnc_g  = (const float*)d_in[11];
  const float* lnc_b  = (const float*)d_in[12];
  const float* lnv_g  = (const float*)d_in[13];
  const float* lnv_b  = (const float*)d_in[14];
  const float* lnm_g  = (const float*)d_in[15];
  const float* lnm_b  = (const float*)d_in[16];
  float* x_out = (float*)d_out;

  char* ws = (char*)d_ws;
  float* TMP = (float*)(ws);                         // 4*512*4096*4  = 33.55 MB
  float* QK  = (float*)(ws + ((size_t)34<<20));      // 4*256*4096*4  = 16.78 MB
  float* XP  = (float*)(ws + ((size_t)51<<20));      // 16.78 MB
  float* Mt  = (float*)(ws + ((size_t)68<<20));      // 256*512*4 = 0.5 MB
  float* QBK = (float*)(ws + ((size_t)69<<20));      // 1 KB

  // one-time precomputes (cheap; rerun every call for graph-capture safety)
  gemm_tn<<<dim3(CO/64, CIN/64), 256, 0, stream>>>(k_w, q_w, Mt);
  qbk_kernel<<<1, CIN, 0, stream>>>(q_b, k_w, QBK);

  // patchify conv + bias -> TMP; x_out = LN_c(TMP)
  gemm_conv<<<dim3(HO, CO/64, NB), 256, 0, stream>>>(conv_w, conv_b, x_in, TMP);
  ln_channel<false><<<dim3(TT/64, NB), 256, 0, stream>>>(TMP, lnc_g, lnc_b, x_out);

  for (int it = 0; it < 3; ++it) {
    // qk[i][t] = Mt[i][:] . x_out[:][t] + qbk[i]
    gemm_f32<CO><<<dim3(TT/64, CIN/64, NB), 256, 0, stream>>>(Mt, QBK, x_out, QK, TT, CIN);
    // softmax logits + p-weighted pooling of x_in
    att_xp<<<dim3(TT/64, NB), 256, 0, stream>>>(QK, x_in, XP);
    // update = v_w . xp + v_b -> TMP; x_out += LN(TMP)
    gemm_f32<CIN><<<dim3(TT/64, CO/64, NB), 256, 0, stream>>>(v_w, v_b, XP, TMP, TT, CO);
    ln_channel<true><<<dim3(TT/64, NB), 256, 0, stream>>>(TMP, lnv_g, lnv_b, x_out);
    // mlp -> TMP; x_out += LN(TMP)
    gemm_f32<CO><<<dim3(TT/64, CO/64, NB), 256, 0, stream>>>(mlp_w, mlp_b, x_out, TMP, TT, CO);
    ln_channel<true><<<dim3(TT/64, NB), 256, 0, stream>>>(TMP, lnm_g, lnm_b, x_out);
  }
}

// Round 4
// 1237.510 us; speedup vs baseline: 1.1955x; 1.1955x over previous
//
#include <hip/hip_runtime.h>

#define NB 4
#define CIN 256
#define CO 512
#define HH 128
#define WW 128
#define PP (HH*WW)     // 16384
#define HO 64
#define TT (HO*HO)     // 4096
#define EPSL 1e-5f

typedef unsigned short u16;
typedef unsigned int   u32;
typedef __attribute__((ext_vector_type(8))) short short8;
typedef __attribute__((ext_vector_type(4))) short short4v;
typedef __attribute__((ext_vector_type(4))) float f32x4;

__device__ __forceinline__ float b2f(u16 u){
  union{float f; u32 i;} x; x.i = ((u32)u)<<16; return x.f;
}
__device__ __forceinline__ u16 f2b(float f){
  union{float f; u32 i;} x; x.f = f;
  u32 r = x.i + 0x7fffu + ((x.i>>16)&1u);   // RNE
  return (u16)(r>>16);
}

// ---------------------------------------------------------------------------
// Fused GEMM + channel-LayerNorm + residual-update of split x_out (XS).
// D[t][c] = sum_k A[t][k]*B[c][k] + bias[c]  (A,B split bf16 hi/lo, 3 MFMAs)
// then per t-row LN over c=512; XS = (MODE? rec(XS) : 0) + LN result, stored
// as split bf16 pair. Block: 512 thr = 8 waves (2m x 4n), BM=32, BN=512.
// ---------------------------------------------------------------------------
template<int K, int MODE>
__global__ __launch_bounds__(512) void gemm_ln(
    const u16* __restrict__ Ah, const u16* __restrict__ Al,   // (NB*TT, K)
    const u16* __restrict__ Bh, const u16* __restrict__ Bl,   // (CO, K)
    const float* __restrict__ bias,
    const float* __restrict__ g, const float* __restrict__ be,
    u16* __restrict__ XSh, u16* __restrict__ XSl)             // (NB*TT, CO)
{
  const int b = blockIdx.z;
  const int t0 = blockIdx.x * 32;
  const int tid = threadIdx.x;
  const int wid = tid >> 6, lane = tid & 63;
  const int wm = wid >> 2, wn = wid & 3;       // wave tile: 16t x 128c
  const int lr = lane & 15, lg = lane >> 4;

  __shared__ u16 AsH[32][40];
  __shared__ u16 AsL[32][40];
  __shared__ float red[2][32][4];

  f32x4 acc[8] = {};
  const size_t abase = ((size_t)b*TT + t0)*K;

  for (int k0 = 0; k0 < K; k0 += 32) {
    { // stage A tile 32x32 hi+lo: 256 chunks of 8B per buffer
      int ch = tid & 255;
      int row = ch >> 3, ko = (ch & 7)*4;
      if (tid < 256)
        *(short4v*)(&AsH[row][ko]) = *(const short4v*)(Ah + abase + (size_t)row*K + k0 + ko);
      else
        *(short4v*)(&AsL[row][ko]) = *(const short4v*)(Al + abase + (size_t)row*K + k0 + ko);
    }
    __syncthreads();
    short8 ah = *(const short8*)(&AsH[wm*16 + lr][lg*8]);
    short8 al = *(const short8*)(&AsL[wm*16 + lr][lg*8]);
    #pragma unroll
    for (int nr = 0; nr < 8; ++nr) {
      size_t boff = (size_t)(wn*128 + nr*16 + lr)*K + k0 + lg*8;
      short8 bh = *(const short8*)(Bh + boff);
      short8 bl = *(const short8*)(Bl + boff);
      acc[nr] = __builtin_amdgcn_mfma_f32_16x16x32_bf16(ah, bh, acc[nr], 0,0,0);
      acc[nr] = __builtin_amdgcn_mfma_f32_16x16x32_bf16(ah, bl, acc[nr], 0,0,0);
      acc[nr] = __builtin_amdgcn_mfma_f32_16x16x32_bf16(al, bh, acc[nr], 0,0,0);
    }
    __syncthreads();
  }

  // epilogue: bias, LN stats, residual update, split store
  float vreg[8][4];
  float s[4] = {0,0,0,0}, s2[4] = {0,0,0,0};
  #pragma unroll
  for (int nr = 0; nr < 8; ++nr) {
    int col = wn*128 + nr*16 + lr;
    float bs = bias[col];
    #pragma unroll
    for (int j = 0; j < 4; ++j) {
      float v = acc[nr][j] + bs;
      vreg[nr][j] = v; s[j] += v; s2[j] += v*v;
    }
  }
  #pragma unroll
  for (int mask = 1; mask <= 8; mask <<= 1) {
    #pragma unroll
    for (int j = 0; j < 4; ++j) {
      s[j]  += __shfl_xor(s[j],  mask, 64);
      s2[j] += __shfl_xor(s2[j], mask, 64);
    }
  }
  const int rl = wm*16 + lg*4;
  if (lr == 0) {
    #pragma unroll
    for (int j = 0; j < 4; ++j) { red[0][rl+j][wn] = s[j]; red[1][rl+j][wn] = s2[j]; }
  }
  __syncthreads();
  float mu[4], rs[4];
  #pragma unroll
  for (int j = 0; j < 4; ++j) {
    float S  = red[0][rl+j][0]+red[0][rl+j][1]+red[0][rl+j][2]+red[0][rl+j][3];
    float S2 = red[1][rl+j][0]+red[1][rl+j][1]+red[1][rl+j][2]+red[1][rl+j][3];
    float m_ = S*(1.f/CO);
    float var = S2*(1.f/CO) - m_*m_;
    mu[j] = m_; rs[j] = rsqrtf(var + EPSL);
  }
  #pragma unroll
  for (int nr = 0; nr < 8; ++nr) {
    int col = wn*128 + nr*16 + lr;
    float gg = g[col], bb = be[col];
    #pragma unroll
    for (int j = 0; j < 4; ++j) {
      size_t gt = (size_t)b*TT + t0 + rl + j;
      size_t xi = gt*CO + col;
      float r = gg*(vreg[nr][j]-mu[j])*rs[j] + bb;
      float nv = MODE ? (b2f(XSh[xi]) + b2f(XSl[xi]) + r) : r;
      u16 h = f2b(nv);
      XSh[xi] = h;
      XSl[xi] = f2b(nv - b2f(h));
    }
  }
}

// ---------------------------------------------------------------------------
// qk GEMM: QK[t][i] = sum_k XS[t][k]*Mt[i][k] + QBK[i].  BM=128, BN=64,
// 256 thr = 4 waves (2x2), m-rep 4, n-rep 2. f32 out.
// ---------------------------------------------------------------------------
__global__ __launch_bounds__(256) void gemm_qk(
    const u16* __restrict__ Ah, const u16* __restrict__ Al,   // XS (NB*TT, 512)
    const u16* __restrict__ Bh, const u16* __restrict__ Bl,   // Mt (256, 512)
    const float* __restrict__ bias,                            // QBK
    float* __restrict__ OUT)                                   // (NB*TT, 256)
{
  const int b = blockIdx.z;
  const int t0 = blockIdx.x*128, n0 = blockIdx.y*64;
  const int tid = threadIdx.x;
  const int wid = tid>>6, lane = tid&63;
  const int wm = wid>>1, wn = wid&1;
  const int lr = lane&15, lg = lane>>4;
  const int K = 512;

  __shared__ u16 AsH[128][40];
  __shared__ u16 AsL[128][40];
  f32x4 acc[4][2] = {};
  const size_t abase = ((size_t)b*TT + t0)*K;

  for (int k0 = 0; k0 < K; k0 += 32) {
    #pragma unroll
    for (int p = 0; p < 4; ++p) {
      int ch = tid + (p&1)*256;          // 0..511
      int row = ch>>2, ko = (ch&3)*8;
      if (p < 2)
        *(short8*)(&AsH[row][ko]) = *(const short8*)(Ah + abase + (size_t)row*K + k0 + ko);
      else
        *(short8*)(&AsL[row][ko]) = *(const short8*)(Al + abase + (size_t)row*K + k0 + ko);
    }
    __syncthreads();
    short8 bh[2], bl[2];
    #pragma unroll
    for (int nr = 0; nr < 2; ++nr) {
      size_t boff = (size_t)(n0 + wn*32 + nr*16 + lr)*K + k0 + lg*8;
      bh[nr] = *(const short8*)(Bh + boff);
      bl[nr] = *(const short8*)(Bl + boff);
    }
    #pragma unroll
    for (int mr = 0; mr < 4; ++mr) {
      int row = wm*64 + mr*16 + lr;
      short8 ah = *(const short8*)(&AsH[row][lg*8]);
      short8 al = *(const short8*)(&AsL[row][lg*8]);
      #pragma unroll
      for (int nr = 0; nr < 2; ++nr) {
        acc[mr][nr] = __builtin_amdgcn_mfma_f32_16x16x32_bf16(ah, bh[nr], acc[mr][nr],0,0,0);
        acc[mr][nr] = __builtin_amdgcn_mfma_f32_16x16x32_bf16(ah, bl[nr], acc[mr][nr],0,0,0);
        acc[mr][nr] = __builtin_amdgcn_mfma_f32_16x16x32_bf16(al, bh[nr], acc[mr][nr],0,0,0);
      }
    }
    __syncthreads();
  }
  #pragma unroll
  for (int mr = 0; mr < 4; ++mr) {
    #pragma unroll
    for (int nr = 0; nr < 2; ++nr) {
      int col = n0 + wn*32 + nr*16 + lr;
      float bs = bias[col];
      #pragma unroll
      for (int j = 0; j < 4; ++j) {
        int row = t0 + wm*64 + mr*16 + lg*4 + j;
        OUT[((size_t)b*TT + row)*CIN + col] = acc[mr][nr][j] + bs;
      }
    }
  }
}

// ---------------------------------------------------------------------------
// Attention: per patch t: logits over 4 window positions from QK-row and XC,
// softmax, p-weighted pooling -> XP split. Wave per t (4 t per wave).
// ---------------------------------------------------------------------------
__global__ __launch_bounds__(256) void att_kernel(
    const float* __restrict__ QK, const u16* __restrict__ XCh, const u16* __restrict__ XCl,
    u16* __restrict__ XPh, u16* __restrict__ XPl)
{
  const int wid = threadIdx.x >> 6, lane = threadIdx.x & 63;
  const size_t gt0 = (size_t)blockIdx.x*16 + wid*4;
  for (int it = 0; it < 4; ++it) {
    const size_t gt = gt0 + it;
    float a[4] = {0.f,0.f,0.f,0.f};
    float xw[4][4];
    #pragma unroll
    for (int ch = 0; ch < 4; ++ch) {
      int i = ch*64 + lane;
      float qv = QK[gt*CIN + i];
      #pragma unroll
      for (int w = 0; w < 4; ++w) {
        size_t xo = gt*1024 + (size_t)w*256 + i;
        float x = b2f(XCh[xo]) + b2f(XCl[xo]);
        xw[ch][w] = x;
        a[w] += qv * x;
      }
    }
    #pragma unroll
    for (int w = 0; w < 4; ++w)
      for (int st = 1; st < 64; st <<= 1)
        a[w] += __shfl_xor(a[w], st, 64);
    float m = fmaxf(fmaxf(a[0],a[1]), fmaxf(a[2],a[3]));
    float e0 = __expf(a[0]-m), e1 = __expf(a[1]-m), e2 = __expf(a[2]-m), e3 = __expf(a[3]-m);
    float inv = 1.f/(e0+e1+e2+e3);
    float p0 = e0*inv, p1 = e1*inv, p2 = e2*inv, p3 = e3*inv;
    #pragma unroll
    for (int ch = 0; ch < 4; ++ch) {
      int i = ch*64 + lane;
      float xp = p0*xw[ch][0] + p1*xw[ch][1] + p2*xw[ch][2] + p3*xw[ch][3];
      u16 h = f2b(xp);
      XPh[gt*CIN + i] = h;
      XPl[gt*CIN + i] = f2b(xp - b2f(h));
    }
  }
}

// ---------------------------------------------------------------------------
// Build XC: XC[b][t][w*256+i] = split(x_in[b][i][2ho+(w>>1)][2wo+(w&1)]).
// Block: (ho, iblk of 32 ch, b); LDS tile 32 x 256 f32.
// ---------------------------------------------------------------------------
__global__ __launch_bounds__(256) void xc_build(
    const float* __restrict__ x_in, u16* __restrict__ XCh, u16* __restrict__ XCl)
{
  const int ho = blockIdx.x, iblk = blockIdx.y, b = blockIdx.z;
  const int tid = threadIdx.x;
  __shared__ float Ls[32][256];
  {
    const int ii = tid >> 3, q = tid & 7;
    const float4* src = (const float4*)(x_in + ((size_t)(b*CIN + iblk*32 + ii)*PP + (size_t)ho*256));
    #pragma unroll
    for (int p = 0; p < 8; ++p) {
      float4 v = src[q + p*8];
      *(float4*)&Ls[ii][(q + p*8)*4] = v;
    }
  }
  __syncthreads();
  {
    const int wo = tid >> 2, w = tid & 3;
    const int colbase = (w>>1)*128 + 2*wo + (w&1);
    u16 hb[32], lb[32];
    #pragma unroll
    for (int ii = 0; ii < 32; ++ii) {
      float v = Ls[ii][colbase];
      u16 h = f2b(v); hb[ii] = h; lb[ii] = f2b(v - b2f(h));
    }
    size_t t = (size_t)b*TT + ho*64 + wo;
    size_t dst = t*1024 + (size_t)w*256 + iblk*32;
    #pragma unroll
    for (int c = 0; c < 4; ++c) {
      short8 hv, lv;
      #pragma unroll
      for (int e = 0; e < 8; ++e) { hv[e] = (short)hb[c*8+e]; lv[e] = (short)lb[c*8+e]; }
      *(short8*)(XCh + dst + c*8) = hv;
      *(short8*)(XCl + dst + c*8) = lv;
    }
  }
}

// ---------------------------------------------------------------------------
// Final: d_out[b][c][t] = rec(XS[b][t][c])  (LDS-tiled transpose, 64x64)
// ---------------------------------------------------------------------------
__global__ __launch_bounds__(256) void out_transpose(
    const u16* __restrict__ XSh, const u16* __restrict__ XSl, float* __restrict__ xout)
{
  const int b = blockIdx.z, c0 = blockIdx.y*64, t0l = blockIdx.x*64;
  const int tid = threadIdx.x;
  __shared__ float Ts[64][68];   // [c][t]
  #pragma unroll
  for (int p = 0; p < 2; ++p) {
    int idx = tid + p*256;       // 0..511
    int row = idx >> 3, ko = (idx & 7)*8;
    size_t off = ((size_t)b*TT + t0l + row)*CO + c0 + ko;
    short8 h8 = *(const short8*)(XSh + off);
    short8 l8 = *(const short8*)(XSl + off);
    #pragma unroll
    for (int e = 0; e < 8; ++e)
      Ts[ko + e][row] = b2f((u16)h8[e]) + b2f((u16)l8[e]);
  }
  __syncthreads();
  const int cl = tid >> 2, tq = tid & 3;
  #pragma unroll
  for (int p = 0; p < 4; ++p) {
    int t4 = (tq + p*4)*4;
    float4 v = *(const float4*)&Ts[cl][t4];
    *(float4*)(xout + ((size_t)b*CO + c0 + cl)*TT + t0l + t4) = v;
  }
}

// ---------------------------------------------------------------------------
// Prep kernels
// ---------------------------------------------------------------------------
__global__ void split_pack(const float* __restrict__ src, u16* __restrict__ h,
                           u16* __restrict__ l, int n){
  int i = blockIdx.x*256 + threadIdx.x;
  if (i < n) { float v = src[i]; u16 hh = f2b(v); h[i]=hh; l[i]=f2b(v - b2f(hh)); }
}

__global__ void conv_pack(const float* __restrict__ cw, u16* __restrict__ h,
                          u16* __restrict__ l){
  int e = blockIdx.x*256 + threadIdx.x;       // < 512*1024
  int o = e >> 10, r = e & 1023, w = r >> 8, i = r & 255;
  float v = cw[o*1024 + i*4 + w];
  u16 hh = f2b(v); h[e]=hh; l[e]=f2b(v - b2f(hh));
}

// Mt[i][j] = sum_f k_w[f][i] * q_w[f][j]   (256 x 512)
__global__ __launch_bounds__(256) void gemm_tn(
    const float* __restrict__ A, const float* __restrict__ B, float* __restrict__ Mt)
{
  const int i0 = blockIdx.y*64, j0 = blockIdx.x*64;
  const int tid = threadIdx.x, tx = tid & 15, ty = tid >> 4;
  __shared__ float As[16][64];
  __shared__ float Bs[16][64];
  float acc[4][4] = {};
  for (int f0 = 0; f0 < CO; f0 += 16) {
    int tt = tid & 63, kkb = tid >> 6;
    #pragma unroll
    for (int s = 0; s < 4; ++s) {
      As[kkb+s*4][tt] = A[(size_t)(f0+kkb+s*4)*CIN + i0 + tt];
      Bs[kkb+s*4][tt] = B[(size_t)(f0+kkb+s*4)*CO  + j0 + tt];
    }
    __syncthreads();
    #pragma unroll
    for (int kk = 0; kk < 16; ++kk) {
      float4 av = *reinterpret_cast<const float4*>(&As[kk][ty*4]);
      float4 bv = *reinterpret_cast<const float4*>(&Bs[kk][tx*4]);
      float a[4] = {av.x,av.y,av.z,av.w}, c[4] = {bv.x,bv.y,bv.z,bv.w};
      #pragma unroll
      for (int j = 0; j < 4; ++j)
        #pragma unroll
        for (int i = 0; i < 4; ++i) acc[j][i] += a[j]*c[i];
    }
    __syncthreads();
  }
  #pragma unroll
  for (int j = 0; j < 4; ++j) {
    float4 r = make_float4(acc[j][0], acc[j][1], acc[j][2], acc[j][3]);
    *reinterpret_cast<float4*>(&Mt[(size_t)(i0+ty*4+j)*CO + j0 + tx*4]) = r;
  }
}

__global__ void qbk_kernel(const float* __restrict__ q_b,
                           const float* __restrict__ k_w, float* __restrict__ qbk)
{
  int i = threadIdx.x;
  float s = 0.f;
  for (int f = 0; f < CO; ++f) s += q_b[f]*k_w[(size_t)f*CIN + i];
  qbk[i] = s;
}

// ---------------------------------------------------------------------------
extern "C" void kernel_launch(void* const* d_in, const int* in_sizes, int n_in,
                              void* d_out, int out_size, void* d_ws, size_t ws_size,
                              hipStream_t stream) {
  const float* x_in   = (const float*)d_in[0];
  const float* conv_w = (const float*)d_in[1];
  const float* conv_b = (const float*)d_in[2];
  const float* k_w    = (const float*)d_in[3];
  const float* q_w    = (const float*)d_in[5];
  const float* q_b    = (const float*)d_in[6];
  const float* v_w    = (const float*)d_in[7];
  const float* v_b    = (const float*)d_in[8];
  const float* mlp_w  = (const float*)d_in[9];
  const float* mlp_b  = (const float*)d_in[10];
  const float* lnc_g  = (const float*)d_in[11];
  const float* lnc_b  = (const float*)d_in[12];
  const float* lnv_g  = (const float*)d_in[13];
  const float* lnv_b  = (const float*)d_in[14];
  const float* lnm_g  = (const float*)d_in[15];
  const float* lnm_b  = (const float*)d_in[16];
  float* x_out = (float*)d_out;

  char* ws = (char*)d_ws;
  const size_t MBy = (size_t)1<<20;
  u16* XCh = (u16*)(ws + 0*MBy);          // 32 MiB (16384 x 1024)
  u16* XCl = (u16*)(ws + 32*MBy);         // 32 MiB
  u16* XSh = (u16*)(ws + 64*MBy);         // 16 MiB (16384 x 512)
  u16* XSl = (u16*)(ws + 80*MBy);         // 16 MiB
  float* QK = (float*)(ws + 96*MBy);      // 16 MiB (16384 x 256 f32)
  u16* XPh = (u16*)(ws + 112*MBy);        // 8 MiB (16384 x 256)
  u16* XPl = (u16*)(ws + 120*MBy);        // 8 MiB
  u16* WCh = (u16*)(ws + 128*MBy);        // 1 MiB (512 x 1024)
  u16* WCl = (u16*)(ws + 129*MBy);
  u16* MWh = (u16*)(ws + 130*MBy);        // 0.5 MiB (512 x 512)
  u16* MWl = (u16*)(ws + 130*MBy + 512*1024);
  u16* VWh = (u16*)(ws + 131*MBy);        // 0.25 MiB (512 x 256)
  u16* VWl = (u16*)(ws + 131*MBy + 256*1024);
  u16* MtH = (u16*)(ws + 131*MBy + 512*1024); // 0.25 MiB (256 x 512)
  u16* MtL = (u16*)(ws + 131*MBy + 768*1024);
  float* MtF = (float*)(ws + 132*MBy);    // 0.5 MiB f32
  float* QBK = (float*)(ws + 132*MBy + 512*1024);

  // --- prep (every call; graph-capture safe) ---
  conv_pack<<<2048, 256, 0, stream>>>(conv_w, WCh, WCl);
  split_pack<<<512, 256, 0, stream>>>(v_w, VWh, VWl, CO*CIN);
  split_pack<<<1024, 256, 0, stream>>>(mlp_w, MWh, MWl, CO*CO);
  gemm_tn<<<dim3(CO/64, CIN/64), 256, 0, stream>>>(k_w, q_w, MtF);
  qbk_kernel<<<1, CIN, 0, stream>>>(q_b, k_w, QBK);
  split_pack<<<512, 256, 0, stream>>>(MtF, MtH, MtL, CIN*CO);
  xc_build<<<dim3(HO, 8, NB), 256, 0, stream>>>(x_in, XCh, XCl);

  // --- conv + LN_c -> XS (fresh) ---
  gemm_ln<1024,0><<<dim3(TT/32, 1, NB), 512, 0, stream>>>(
      XCh, XCl, WCh, WCl, conv_b, lnc_g, lnc_b, XSh, XSl);

  for (int it = 0; it < 3; ++it) {
    gemm_qk<<<dim3(TT/128, CIN/64, NB), 256, 0, stream>>>(
        XSh, XSl, MtH, MtL, QBK, QK);
    att_kernel<<<(NB*TT)/16, 256, 0, stream>>>(QK, XCh, XCl, XPh, XPl);
    gemm_ln<256,1><<<dim3(TT/32, 1, NB), 512, 0, stream>>>(
        XPh, XPl, VWh, VWl, v_b, lnv_g, lnv_b, XSh, XSl);
    gemm_ln<512,1><<<dim3(TT/32, 1, NB), 512, 0, stream>>>(
        XSh, XSl, MWh, MWl, mlp_b, lnm_g, lnm_b, XSh, XSl);
  }

  // --- emit f32 (b, c, t) ---
  out_transpose<<<dim3(TT/64, CO/64, NB), 256, 0, stream>>>(XSh, XSl, x_out);
}

// Round 5
// 719.001 us; speedup vs baseline: 2.0576x; 1.7212x over previous
//
#include <hip/hip_runtime.h>

#define NB 4
#define CIN 256
#define CO 512
#define HH 128
#define WW 128
#define PP (HH*WW)     // 16384
#define HO 64
#define TT (HO*HO)     // 4096
#define EPSL 1e-5f

typedef unsigned short u16;
typedef unsigned int   u32;
typedef __attribute__((ext_vector_type(8))) short short8;
typedef __attribute__((ext_vector_type(4))) short short4v;
typedef __attribute__((ext_vector_type(4))) float f32x4;

__device__ __forceinline__ float b2f(u16 u){
  union{float f; u32 i;} x; x.i = ((u32)u)<<16; return x.f;
}
__device__ __forceinline__ u16 f2b(float f){
  union{float f; u32 i;} x; x.f = f;
  u32 r = x.i + 0x7fffu + ((x.i>>16)&1u);   // RNE
  return (u16)(r>>16);
}

__device__ __forceinline__ void gl16(const u16* g, u16* l){
  __builtin_amdgcn_global_load_lds((const __attribute__((address_space(1))) void*)g,
                                   (__attribute__((address_space(3))) void*)l, 16, 0, 0);
}

// ---------------------------------------------------------------------------
// Generic split-bf16 MFMA GEMM, 128x128 tile, 4 waves (wave-tile 64x64),
// BK=32, double-buffered LDS (64 KiB) staged via global_load_lds with
// counted vmcnt. OUT[row][col] = sum_k A[row][k]*B[col][k] + bias.
// EPI 0: f32 out, bias per-row.  EPI 1: split-pair out, bias per-col.
// LDS chunk swizzle: c' = c ^ ((row>>1)&3)  (16B chunks, 64B rows) -> 2-way.
// ---------------------------------------------------------------------------
template<int K, int EPI>
__global__ __launch_bounds__(256) void gemm_t(
    const u16* __restrict__ Ah, const u16* __restrict__ Al, size_t aBS,
    const u16* __restrict__ Bh, const u16* __restrict__ Bl, size_t bBS,
    const float* __restrict__ bias,
    float* __restrict__ OUTf, u16* __restrict__ OPh, u16* __restrict__ OPl,
    size_t oBS, int oLd)
{
  const int z = blockIdx.z;
  const int r0 = blockIdx.x*128, c0 = blockIdx.y*128;
  const int tid = threadIdx.x, wid = tid>>6, lane = tid&63;
  const int wm = wid>>1, wn = wid&1, lr = lane&15, lg = lane>>4;

  extern __shared__ u16 sm[];   // 2 bufs x (Ah 4096 | Al 4096 | Bh 4096 | Bl 4096) u16

  const size_t abase = (size_t)z*aBS + (size_t)r0*K;
  const size_t bbase = (size_t)z*bBS + (size_t)c0*K;

  f32x4 acc[4][4] = {};

  // staging geometry: thread covers chunks q0,q1 of each 512-chunk tile
  const int q0 = tid, q1 = tid+256;
  const int r_0 = q0>>2, c_0 = q0&3;
  const int r_1 = q1>>2, c_1 = q1&3;
  const size_t go0 = (size_t)r_0*K + (size_t)((c_0 ^ ((r_0>>1)&3))*8);
  const size_t go1 = (size_t)r_1*K + (size_t)((c_1 ^ ((r_1>>1)&3))*8);

  const int NS = K/32;
  #pragma unroll 1
  for (int s = 0; s < NS; ++s) {
    if (s == 0) {   // prologue stage of buf0
      u16* buf = sm;
      gl16(Ah+abase+go0, buf+q0*8);        gl16(Ah+abase+go1, buf+q1*8);
      gl16(Al+abase+go0, buf+4096+q0*8);   gl16(Al+abase+go1, buf+4096+q1*8);
      gl16(Bh+bbase+go0, buf+8192+q0*8);   gl16(Bh+bbase+go1, buf+8192+q1*8);
      gl16(Bl+bbase+go0, buf+12288+q0*8);  gl16(Bl+bbase+go1, buf+12288+q1*8);
    }
    if (s+1 < NS) {  // stage next tile, then wait only for current (8 newest stay in flight)
      u16* buf = sm + ((s+1)&1)*16384;
      const size_t ko = (size_t)(s+1)*32;
      gl16(Ah+abase+go0+ko, buf+q0*8);        gl16(Ah+abase+go1+ko, buf+q1*8);
      gl16(Al+abase+go0+ko, buf+4096+q0*8);   gl16(Al+abase+go1+ko, buf+4096+q1*8);
      gl16(Bh+bbase+go0+ko, buf+8192+q0*8);   gl16(Bh+bbase+go1+ko, buf+8192+q1*8);
      gl16(Bl+bbase+go0+ko, buf+12288+q0*8);  gl16(Bl+bbase+go1+ko, buf+12288+q1*8);
      asm volatile("s_waitcnt vmcnt(8)" ::: "memory");
    } else {
      asm volatile("s_waitcnt vmcnt(0)" ::: "memory");
    }
    __builtin_amdgcn_s_barrier();
    __builtin_amdgcn_sched_barrier(0);
    {
      const u16* buf = sm + (s&1)*16384;
      const u16* Ax = buf, *Ay = buf+4096, *Bx = buf+8192, *By = buf+12288;
      short8 bh[4], bl[4];
      #pragma unroll
      for (int nf=0; nf<4; ++nf) {
        int row = wn*64 + nf*16 + lr;
        int off = row*32 + ((lg ^ ((row>>1)&3))<<3);
        bh[nf] = *(const short8*)(Bx+off);
        bl[nf] = *(const short8*)(By+off);
      }
      #pragma unroll
      for (int mf=0; mf<4; ++mf) {
        int row = wm*64 + mf*16 + lr;
        int off = row*32 + ((lg ^ ((row>>1)&3))<<3);
        short8 ah = *(const short8*)(Ax+off);
        short8 al = *(const short8*)(Ay+off);
        #pragma unroll
        for (int nf=0; nf<4; ++nf) {
          acc[mf][nf] = __builtin_amdgcn_mfma_f32_16x16x32_bf16(ah, bh[nf], acc[mf][nf],0,0,0);
          acc[mf][nf] = __builtin_amdgcn_mfma_f32_16x16x32_bf16(ah, bl[nf], acc[mf][nf],0,0,0);
          acc[mf][nf] = __builtin_amdgcn_mfma_f32_16x16x32_bf16(al, bh[nf], acc[mf][nf],0,0,0);
        }
      }
    }
    __builtin_amdgcn_sched_barrier(0);
    __builtin_amdgcn_s_barrier();
  }
  __builtin_amdgcn_sched_barrier(0);

  #pragma unroll
  for (int mf=0; mf<4; ++mf) {
    #pragma unroll
    for (int nf=0; nf<4; ++nf) {
      int col = c0 + wn*64 + nf*16 + lr;
      #pragma unroll
      for (int j=0; j<4; ++j) {
        int row = r0 + wm*64 + mf*16 + lg*4 + j;
        float v = acc[mf][nf][j] + (EPI==0 ? bias[row] : bias[col]);
        size_t oi = (size_t)z*oBS + (size_t)row*oLd + col;
        if (EPI==0) {
          OUTf[oi] = v;
        } else {
          u16 h = f2b(v);
          OPh[oi] = h;
          OPl[oi] = f2b(v - b2f(h));
        }
      }
    }
  }
}

// ---------------------------------------------------------------------------
// Channel LayerNorm from split TMP pair; XS = (ADD? rec(XS) : 0) + LN.
// Wave per row (512 channels = 64 lanes x 8).
// ---------------------------------------------------------------------------
template<int ADD>
__global__ __launch_bounds__(256) void ln_split(
    const u16* __restrict__ TPh, const u16* __restrict__ TPl,
    const float* __restrict__ g, const float* __restrict__ be,
    u16* __restrict__ XSh, u16* __restrict__ XSl)
{
  const int wid = threadIdx.x>>6, lane = threadIdx.x&63;
  const size_t row = (size_t)blockIdx.x*4 + wid;
  const size_t base = row*CO + lane*8;
  short8 h8 = *(const short8*)(TPh + base);
  short8 l8 = *(const short8*)(TPl + base);
  float v[8]; float s=0.f, s2=0.f;
  #pragma unroll
  for (int e=0;e<8;++e){ v[e]=b2f((u16)h8[e])+b2f((u16)l8[e]); s+=v[e]; s2+=v[e]*v[e]; }
  #pragma unroll
  for (int m=1;m<64;m<<=1){ s+=__shfl_xor(s,m,64); s2+=__shfl_xor(s2,m,64); }
  float mu = s*(1.f/CO);
  float rstd = rsqrtf(s2*(1.f/CO) - mu*mu + EPSL);
  const int cc0 = lane*8;
  float4 g0 = *(const float4*)(g+cc0), g1 = *(const float4*)(g+cc0+4);
  float4 e0 = *(const float4*)(be+cc0), e1 = *(const float4*)(be+cc0+4);
  float gg[8] = {g0.x,g0.y,g0.z,g0.w,g1.x,g1.y,g1.z,g1.w};
  float bb[8] = {e0.x,e0.y,e0.z,e0.w,e1.x,e1.y,e1.z,e1.w};
  short8 xh, xl;
  if (ADD) { xh = *(const short8*)(XSh+base); xl = *(const short8*)(XSl+base); }
  short8 oh, ol;
  #pragma unroll
  for (int e=0;e<8;++e){
    float r = gg[e]*(v[e]-mu)*rstd + bb[e];
    float nv = ADD ? (b2f((u16)xh[e]) + b2f((u16)xl[e]) + r) : r;
    u16 h = f2b(nv); oh[e]=(short)h; ol[e]=(short)f2b(nv - b2f(h));
  }
  *(short8*)(XSh+base) = oh;
  *(short8*)(XSl+base) = ol;
}

// ---------------------------------------------------------------------------
// Attention: logits from QK (b,i,t f32) and x_in (f32), softmax over the 4
// window positions, p-weighted pooling -> XP pair (b,t,i). 64 t x 4 i-groups.
// ---------------------------------------------------------------------------
__global__ __launch_bounds__(256) void att_xp(
    const float* __restrict__ qk, const float* __restrict__ x_in,
    u16* __restrict__ XPh, u16* __restrict__ XPl)
{
  const int b = blockIdx.y;
  const int tl = threadIdx.x & 63, cg = threadIdx.x >> 6;
  const int t = blockIdx.x*64 + tl;
  const int ho = t >> 6, wo = t & 63;
  const size_t p00 = (size_t)(2*ho)*WW + 2*wo;  // +0,+1,+WW,+WW+1

  float a0=0.f, a1=0.f, a2=0.f, a3=0.f;
  for (int i = cg*64; i < cg*64 + 64; ++i) {
    float qv = qk[((size_t)b*CIN + i)*TT + t];
    const float* xr = x_in + ((size_t)b*CIN + i)*PP + p00;
    float2 x01 = *(const float2*)xr;
    float2 x23 = *(const float2*)(xr + WW);
    a0 += qv*x01.x; a1 += qv*x01.y; a2 += qv*x23.x; a3 += qv*x23.y;
  }
  __shared__ float attp[4][64][4];
  attp[cg][tl][0] = a0; attp[cg][tl][1] = a1;
  attp[cg][tl][2] = a2; attp[cg][tl][3] = a3;
  __syncthreads();
  a0 = attp[0][tl][0] + attp[1][tl][0] + attp[2][tl][0] + attp[3][tl][0];
  a1 = attp[0][tl][1] + attp[1][tl][1] + attp[2][tl][1] + attp[3][tl][1];
  a2 = attp[0][tl][2] + attp[1][tl][2] + attp[2][tl][2] + attp[3][tl][2];
  a3 = attp[0][tl][3] + attp[1][tl][3] + attp[2][tl][3] + attp[3][tl][3];
  float m = fmaxf(fmaxf(a0,a1), fmaxf(a2,a3));
  float ee0 = __expf(a0-m), ee1 = __expf(a1-m), ee2 = __expf(a2-m), ee3 = __expf(a3-m);
  float inv = 1.f/(ee0+ee1+ee2+ee3);
  float p0 = ee0*inv, p1 = ee1*inv, p2 = ee2*inv, p3 = ee3*inv;

  for (int ib = 0; ib < 64; ib += 8) {
    short8 oh, ol;
    #pragma unroll
    for (int e = 0; e < 8; ++e) {
      int i = cg*64 + ib + e;
      const float* xr = x_in + ((size_t)b*CIN + i)*PP + p00;
      float2 x01 = *(const float2*)xr;
      float2 x23 = *(const float2*)(xr + WW);
      float u = p0*x01.x + p1*x01.y + p2*x23.x + p3*x23.y;
      u16 h = f2b(u); oh[e] = (short)h; ol[e] = (short)f2b(u - b2f(h));
    }
    size_t o = ((size_t)b*TT + t)*CIN + cg*64 + ib;
    *(short8*)(XPh + o) = oh;
    *(short8*)(XPl + o) = ol;
  }
}

// ---------------------------------------------------------------------------
// Build XC: XC[b][t][w*256+i] = split(x_in window pixels). (feeds conv GEMM)
// ---------------------------------------------------------------------------
__global__ __launch_bounds__(256) void xc_build(
    const float* __restrict__ x_in, u16* __restrict__ XCh, u16* __restrict__ XCl)
{
  const int ho = blockIdx.x, iblk = blockIdx.y, b = blockIdx.z;
  const int tid = threadIdx.x;
  __shared__ float Ls[32][256];
  {
    const int ii = tid >> 3, q = tid & 7;
    const float4* src = (const float4*)(x_in + ((size_t)(b*CIN + iblk*32 + ii)*PP + (size_t)ho*256));
    #pragma unroll
    for (int p = 0; p < 8; ++p) {
      float4 v = src[q + p*8];
      *(float4*)&Ls[ii][(q + p*8)*4] = v;
    }
  }
  __syncthreads();
  {
    const int wo = tid >> 2, w = tid & 3;
    const int colbase = (w>>1)*128 + 2*wo + (w&1);
    u16 hb[32], lb[32];
    #pragma unroll
    for (int ii = 0; ii < 32; ++ii) {
      float v = Ls[ii][colbase];
      u16 h = f2b(v); hb[ii] = h; lb[ii] = f2b(v - b2f(h));
    }
    size_t t = (size_t)b*TT + ho*64 + wo;
    size_t dst = t*1024 + (size_t)w*256 + iblk*32;
    #pragma unroll
    for (int c = 0; c < 4; ++c) {
      short8 hv, lv;
      #pragma unroll
      for (int e = 0; e < 8; ++e) { hv[e] = (short)hb[c*8+e]; lv[e] = (short)lb[c*8+e]; }
      *(short8*)(XCh + dst + c*8) = hv;
      *(short8*)(XCl + dst + c*8) = lv;
    }
  }
}

// ---------------------------------------------------------------------------
// Final: d_out[b][c][t] = rec(XS[b][t][c])  (LDS-tiled transpose, 64x64)
// ---------------------------------------------------------------------------
__global__ __launch_bounds__(256) void out_transpose(
    const u16* __restrict__ XSh, const u16* __restrict__ XSl, float* __restrict__ xout)
{
  const int b = blockIdx.z, c0 = blockIdx.y*64, t0l = blockIdx.x*64;
  const int tid = threadIdx.x;
  __shared__ float Ts[64][68];   // [c][t]
  #pragma unroll
  for (int p = 0; p < 2; ++p) {
    int idx = tid + p*256;       // 0..511
    int row = idx >> 3, ko = (idx & 7)*8;
    size_t off = ((size_t)b*TT + t0l + row)*CO + c0 + ko;
    short8 h8 = *(const short8*)(XSh + off);
    short8 l8 = *(const short8*)(XSl + off);
    #pragma unroll
    for (int e = 0; e < 8; ++e)
      Ts[ko + e][row] = b2f((u16)h8[e]) + b2f((u16)l8[e]);
  }
  __syncthreads();
  const int cl = tid >> 2, tq = tid & 3;
  #pragma unroll
  for (int p = 0; p < 4; ++p) {
    int t4 = (tq + p*4)*4;
    float4 v = *(const float4*)&Ts[cl][t4];
    *(float4*)(xout + ((size_t)b*CO + c0 + cl)*TT + t0l + t4) = v;
  }
}

// ---------------------------------------------------------------------------
// Prep kernels
// ---------------------------------------------------------------------------
__global__ void split_pack(const float* __restrict__ src, u16* __restrict__ h,
                           u16* __restrict__ l, int n){
  int i = blockIdx.x*256 + threadIdx.x;
  if (i < n) { float v = src[i]; u16 hh = f2b(v); h[i]=hh; l[i]=f2b(v - b2f(hh)); }
}

__global__ void conv_pack(const float* __restrict__ cw, u16* __restrict__ h,
                          u16* __restrict__ l){
  int e = blockIdx.x*256 + threadIdx.x;       // < 512*1024
  int o = e >> 10, r = e & 1023, w = r >> 8, i = r & 255;
  float v = cw[o*1024 + i*4 + w];
  u16 hh = f2b(v); h[e]=hh; l[e]=f2b(v - b2f(hh));
}

// Mt[i][j] = sum_f k_w[f][i] * q_w[f][j]   (256 x 512), split-pair output
__global__ __launch_bounds__(256) void gemm_tn(
    const float* __restrict__ A, const float* __restrict__ B,
    u16* __restrict__ MtH, u16* __restrict__ MtL)
{
  const int i0 = blockIdx.y*64, j0 = blockIdx.x*64;
  const int tid = threadIdx.x, tx = tid & 15, ty = tid >> 4;
  __shared__ float As[16][64];
  __shared__ float Bs[16][64];
  float acc[4][4] = {};
  for (int f0 = 0; f0 < CO; f0 += 16) {
    int tt = tid & 63, kkb = tid >> 6;
    #pragma unroll
    for (int s = 0; s < 4; ++s) {
      As[kkb+s*4][tt] = A[(size_t)(f0+kkb+s*4)*CIN + i0 + tt];
      Bs[kkb+s*4][tt] = B[(size_t)(f0+kkb+s*4)*CO  + j0 + tt];
    }
    __syncthreads();
    #pragma unroll
    for (int kk = 0; kk < 16; ++kk) {
      float4 av = *reinterpret_cast<const float4*>(&As[kk][ty*4]);
      float4 bv = *reinterpret_cast<const float4*>(&Bs[kk][tx*4]);
      float a[4] = {av.x,av.y,av.z,av.w}, c[4] = {bv.x,bv.y,bv.z,bv.w};
      #pragma unroll
      for (int j = 0; j < 4; ++j)
        #pragma unroll
        for (int i = 0; i < 4; ++i) acc[j][i] += a[j]*c[i];
    }
    __syncthreads();
  }
  #pragma unroll
  for (int j = 0; j < 4; ++j) {
    #pragma unroll
    for (int i = 0; i < 4; ++i) {
      float v = acc[j][i];
      size_t idx = (size_t)(i0+ty*4+j)*CO + j0 + tx*4 + i;
      u16 h = f2b(v);
      MtH[idx] = h; MtL[idx] = f2b(v - b2f(h));
    }
  }
}

__global__ void qbk_kernel(const float* __restrict__ q_b,
                           const float* __restrict__ k_w, float* __restrict__ qbk)
{
  int i = threadIdx.x;
  float s = 0.f;
  for (int f = 0; f < CO; ++f) s += q_b[f]*k_w[(size_t)f*CIN + i];
  qbk[i] = s;
}

// ---------------------------------------------------------------------------
extern "C" void kernel_launch(void* const* d_in, const int* in_sizes, int n_in,
                              void* d_out, int out_size, void* d_ws, size_t ws_size,
                              hipStream_t stream) {
  const float* x_in   = (const float*)d_in[0];
  const float* conv_w = (const float*)d_in[1];
  const float* conv_b = (const float*)d_in[2];
  const float* k_w    = (const float*)d_in[3];
  const float* q_w    = (const float*)d_in[5];
  const float* q_b    = (const float*)d_in[6];
  const float* v_w    = (const float*)d_in[7];
  const float* v_b    = (const float*)d_in[8];
  const float* mlp_w  = (const float*)d_in[9];
  const float* mlp_b  = (const float*)d_in[10];
  const float* lnc_g  = (const float*)d_in[11];
  const float* lnc_b  = (const float*)d_in[12];
  const float* lnv_g  = (const float*)d_in[13];
  const float* lnv_b  = (const float*)d_in[14];
  const float* lnm_g  = (const float*)d_in[15];
  const float* lnm_b  = (const float*)d_in[16];
  float* x_out = (float*)d_out;

  char* ws = (char*)d_ws;
  const size_t MBy = (size_t)1<<20;
  // [0,64): XC pair (alive xc_build -> conv-gemm), then reused:
  u16* XCh = (u16*)(ws + 0*MBy);           // 32 MiB
  u16* XCl = (u16*)(ws + 32*MBy);          // 32 MiB
  u16* XSh = (u16*)(ws + 0*MBy);           // 16 MiB (written by conv-ln, after XC dead)
  u16* XSl = (u16*)(ws + 16*MBy);          // 16 MiB
  u16* XPh = (u16*)(ws + 32*MBy);          // 8 MiB
  u16* XPl = (u16*)(ws + 40*MBy);          // 8 MiB
  float* QK = (float*)(ws + 48*MBy);       // 16 MiB (b,i,t) f32
  u16* TPh = (u16*)(ws + 64*MBy);          // 16 MiB
  u16* TPl = (u16*)(ws + 80*MBy);          // 16 MiB
  u16* WCh = (u16*)(ws + 96*MBy);          // 1 MiB
  u16* WCl = (u16*)(ws + 97*MBy);          // 1 MiB
  u16* MWh = (u16*)(ws + 98*MBy);          // 0.5 MiB
  u16* MWl = (u16*)(ws + 98*MBy + 512*1024);
  u16* VWh = (u16*)(ws + 99*MBy);          // 0.25 MiB
  u16* VWl = (u16*)(ws + 99*MBy + 256*1024);
  u16* MtH = (u16*)(ws + 99*MBy + 512*1024);
  u16* MtL = (u16*)(ws + 99*MBy + 768*1024);
  float* QBK = (float*)(ws + 100*MBy);     // 1 KB

  // --- prep ---
  conv_pack<<<2048, 256, 0, stream>>>(conv_w, WCh, WCl);
  split_pack<<<512, 256, 0, stream>>>(v_w, VWh, VWl, CO*CIN);
  split_pack<<<1024, 256, 0, stream>>>(mlp_w, MWh, MWl, CO*CO);
  gemm_tn<<<dim3(CO/64, CIN/64), 256, 0, stream>>>(k_w, q_w, MtH, MtL);
  qbk_kernel<<<1, CIN, 0, stream>>>(q_b, k_w, QBK);
  xc_build<<<dim3(HO, 8, NB), 256, 0, stream>>>(x_in, XCh, XCl);

  // --- conv -> TP pair; LN -> XS ---
  gemm_t<1024,1><<<dim3(TT/128, 4, NB), 256, 65536, stream>>>(
      XCh, XCl, (size_t)TT*1024, WCh, WCl, (size_t)0, conv_b,
      nullptr, TPh, TPl, (size_t)TT*CO, CO);
  ln_split<0><<<NB*TT/4, 256, 0, stream>>>(TPh, TPl, lnc_g, lnc_b, XSh, XSl);

  for (int it = 0; it < 3; ++it) {
    // QK[b][i][t] = Mt[i][:] . x_out[t][:] + QBK[i]   (A=Mt, B=XS swapped)
    gemm_t<512,0><<<dim3(CIN/128, TT/128, NB), 256, 65536, stream>>>(
        MtH, MtL, (size_t)0, XSh, XSl, (size_t)TT*CO, QBK,
        QK, nullptr, nullptr, (size_t)CIN*TT, TT);
    att_xp<<<dim3(TT/64, NB), 256, 0, stream>>>(QK, x_in, XPh, XPl);
    // update = v_w . xp + v_b -> TP; XS += LN(TP)
    gemm_t<256,1><<<dim3(TT/128, 4, NB), 256, 65536, stream>>>(
        XPh, XPl, (size_t)TT*CIN, VWh, VWl, (size_t)0, v_b,
        nullptr, TPh, TPl, (size_t)TT*CO, CO);
    ln_split<1><<<NB*TT/4, 256, 0, stream>>>(TPh, TPl, lnv_g, lnv_b, XSh, XSl);
    // mlp -> TP; XS += LN(TP)
    gemm_t<512,1><<<dim3(TT/128, 4, NB), 256, 65536, stream>>>(
        XSh, XSl, (size_t)TT*CO, MWh, MWl, (size_t)0, mlp_b,
        nullptr, TPh, TPl, (size_t)TT*CO, CO);
    ln_split<1><<<NB*TT/4, 256, 0, stream>>>(TPh, TPl, lnm_g, lnm_b, XSh, XSl);
  }

  // --- emit f32 (b, c, t) ---
  out_transpose<<<dim3(TT/64, CO/64, NB), 256, 0, stream>>>(XSh, XSl, x_out);
}